// Round 6
// baseline (465.471 us; speedup 1.0000x reference)
//
#include <hip/hip_runtime.h>
#include <hip/hip_bf16.h>

typedef __bf16 bf16;
typedef __attribute__((ext_vector_type(8))) bf16 bf16x8;
typedef __attribute__((ext_vector_type(4))) bf16 bf16x4;
typedef __attribute__((ext_vector_type(4))) float f32x4;
typedef unsigned int uint;

#define SEQ    4096
#define DIM    256
#define NBATCH 4
#define NROWS  (NBATCH*SEQ)      // 16384
#define NEGV   (-6.25e7f)        // -1e9 / sqrt(256)
#define KSPLIT 4
#define KPER   (SEQ/KSPLIT)      // 1024
#define VSTR   40                // V row stride: 32 keys (64B) + 16B pad -> conflict-free b128

__device__ __forceinline__ int imax(int a, int b) { return a > b ? a : b; }
__device__ __forceinline__ int imin(int a, int b) { return a < b ? a : b; }

__device__ __forceinline__ uint pkbf(float lo, float hi) {
    union { bf16 b; unsigned short s; } a, c;
    a.b = (bf16)lo; c.b = (bf16)hi;
    return ((uint)c.s << 16) | (uint)a.s;
}

// ================= weights f32 -> bf16 =================
__global__ __launch_bounds__(256) void cvt_w_kernel(
    const float* __restrict__ w0, const float* __restrict__ w1,
    const float* __restrict__ w2, const float* __restrict__ w3,
    bf16* __restrict__ o0, bf16* __restrict__ o1,
    bf16* __restrict__ o2, bf16* __restrict__ o3)
{
    const float* s; bf16* d;
    switch (blockIdx.y) {
        case 0:  s = w0; d = o0; break;
        case 1:  s = w1; d = o1; break;
        case 2:  s = w2; d = o2; break;
        default: s = w3; d = o3; break;
    }
    int i = (blockIdx.x*256 + threadIdx.x)*4;
    f32x4 v = *(const f32x4*)(s + i);
    bf16x4 b;
#pragma unroll
    for (int j = 0; j < 4; ++j) b[j] = (bf16)v[j];
    *(bf16x4*)(d + i) = b;
}

// ================= projection GEMM: out = X @ W^T + bias =================
// Token tile = 16 -> 1024 blocks (4/CU). 4 waves x 64 out-cols.
// OUT_MODE: 0 = bf16 row-major, 1 = bf16 transposed per batch [4][256][4096], 2 = f32 row-major
template<int OUT_MODE, bool IN_BF16, bool DO_SCALE>
__global__ __launch_bounds__(256, 4) void proj_kernel(
    const void* __restrict__ Xv, const bf16* __restrict__ W,
    const float* __restrict__ bias, void* __restrict__ outv)
{
    __shared__ bf16 X_lds[16*256];   // 8 KB, XOR-swizzled
    const int tid = threadIdx.x;
    const int tok0 = blockIdx.x * 16;

    if (IN_BF16) {
        const bf16* X = (const bf16*)Xv;
#pragma unroll
        for (int i = 0; i < 2; ++i) {
            int g = i*256 + tid;
            int tok = g >> 5, c8 = (g & 31)*8;
            bf16x8 v = *(const bf16x8*)(X + (size_t)(tok0+tok)*DIM + c8);
            *(bf16x8*)(X_lds + tok*256 + (c8 ^ ((tok & 7) << 3))) = v;
        }
    } else {
        const float* X = (const float*)Xv;
#pragma unroll
        for (int i = 0; i < 2; ++i) {
            int g = i*256 + tid;
            int tok = g >> 5, c8 = (g & 31)*8;
            const f32x4* p = (const f32x4*)(X + (size_t)(tok0+tok)*DIM + c8);
            f32x4 a = p[0], b2 = p[1];
            bf16x8 v;
#pragma unroll
            for (int j = 0; j < 4; ++j) { v[j] = (bf16)a[j]; v[4+j] = (bf16)b2[j]; }
            *(bf16x8*)(X_lds + tok*256 + (c8 ^ ((tok & 7) << 3))) = v;
        }
    }
    __syncthreads();

    const int wave = tid >> 6, lane = tid & 63;
    const int l16 = lane & 15, lhi = lane >> 4;
    const int oc0 = wave * 64;

    f32x4 acc[4];
#pragma unroll
    for (int n = 0; n < 4; ++n) acc[n] = (f32x4){0.f,0.f,0.f,0.f};

#pragma unroll
    for (int kk = 0; kk < 8; ++kk) {
        const int koff = kk*32 + 8*lhi;
        bf16x8 af = *(const bf16x8*)(X_lds + l16*256 + (koff ^ ((l16 & 7) << 3)));
        bf16x8 bf_[4];
#pragma unroll
        for (int n = 0; n < 4; ++n) {
            int o = oc0 + n*16 + l16;
            bf_[n] = *(const bf16x8*)(W + (size_t)o*DIM + koff);
        }
#pragma unroll
        for (int n = 0; n < 4; ++n)
            acc[n] = __builtin_amdgcn_mfma_f32_16x16x32_bf16(af, bf_[n], acc[n], 0, 0, 0);
    }

#pragma unroll
    for (int n = 0; n < 4; ++n) {
        const int o = oc0 + n*16 + l16;
        const float bb = bias[o];
        const int tk0 = tok0 + lhi*4;
        if (OUT_MODE == 1) {
            bf16x4 pk;
#pragma unroll
            for (int r = 0; r < 4; ++r) pk[r] = (bf16)(acc[n][r] + bb);
            const int bi = tk0 >> 12, tk = tk0 & (SEQ-1);
            *(bf16x4*)((bf16*)outv + (size_t)bi*DIM*SEQ + (size_t)o*SEQ + tk) = pk;
        } else {
#pragma unroll
            for (int r = 0; r < 4; ++r) {
                float v = acc[n][r] + bb;
                if (DO_SCALE) v *= 0.0625f;
                if (OUT_MODE == 0) ((bf16*)outv)[(size_t)(tk0+r)*DIM + o] = (bf16)v;
                else               ((float*)outv)[(size_t)(tk0+r)*DIM + o] = v;
            }
        }
    }
}

// ================= flash attention v3 (V-stride bug fixed) =================
// Swapped QK^T (S^T via mfma(K,Q)), in-register P redistribution, mt=2
// (32 q-rows/wave), KVBLK=32, double-buffered K/V LDS (1 barrier/tile),
// K-split=4. grid 512 x 256 threads (4 waves).
__global__ __launch_bounds__(256, 2) void attn_kernel(
    const bf16* __restrict__ Qp, const bf16* __restrict__ Kp,
    const bf16* __restrict__ Vt, const int* __restrict__ mask,
    float* __restrict__ pm, float* __restrict__ pl, float* __restrict__ pO)
{
    __shared__ __align__(16) bf16 Kbuf[2][32*256];    // 2 x 16 KB, XOR-swizzled rows
    __shared__ __align__(16) bf16 Vbuf[2][256*VSTR];  // 2 x 20 KB, 80B row stride
    __shared__ int sLb[4];

    const int tid  = threadIdx.x;
    const int wave = tid >> 6, lane = tid & 63;
    const int l16  = lane & 15, lhi = lane >> 4;

    // XCD swizzle: consecutive blocks on an XCD share the same (b, ks) K/V panel
    const int swz = ((blockIdx.x & 7) << 6) | (blockIdx.x >> 3);   // 512 blocks
    const int b   = swz >> 7;
    const int ks  = (swz >> 5) & 3;
    const int qt  = swz & 31;

    const int kb0 = ks * KPER;
    const int q0  = qt*128 + wave*32;
    const size_t bQ = (size_t)b * SEQ * DIM;

    // lengths: lane (lane&31) holds row q0+(lane&31)
    const int mv = mask[b*SEQ + q0 + (lane & 31)];
    int Lw = mv;
#pragma unroll
    for (int w = 1; w < 32; w <<= 1) Lw = imax(Lw, __shfl_xor(Lw, w));
    const int Lq0 = __shfl(mv, l16);
    const int Lq1 = __shfl(mv, 16 + l16);
    if (lane == 0) sLb[wave] = Lw;

    // Q fragments (B-operand of swapped QK): lane l16 = q-col, k = kk*32+8*lhi+j
    bf16x8 qf[2][8];
#pragma unroll
    for (int mt = 0; mt < 2; ++mt) {
        const bf16* qr = Qp + bQ + (size_t)(q0 + mt*16 + l16)*DIM + 8*lhi;
#pragma unroll
        for (int kk = 0; kk < 8; ++kk) qf[mt][kk] = *(const bf16x8*)(qr + kk*32);
    }

    float m_run[2] = {NEGV, NEGV}, l_run[2] = {0.f, 0.f};
    f32x4 oacc[2][16];
#pragma unroll
    for (int mt = 0; mt < 2; ++mt)
#pragma unroll
        for (int t = 0; t < 16; ++t) oacc[mt][t] = (f32x4){0.f,0.f,0.f,0.f};

    const bf16* Ksrc0 = Kp + bQ;
    const bf16* Vsrc0 = Vt + (size_t)b * DIM * SEQ;

    bf16x8 kr[4], vr[4];
    // prologue: stage tile 0 (unconditional; kb0 always in-bounds)
    {
        const bf16* Ks = Ksrc0 + (size_t)kb0*DIM;
        const bf16* Vs = Vsrc0 + kb0;
#pragma unroll
        for (int i = 0; i < 4; ++i) {
            int g = i*256 + tid;
            kr[i] = *(const bf16x8*)(Ks + (size_t)(g >> 5)*DIM + (g & 31)*8);
            vr[i] = *(const bf16x8*)(Vs + (size_t)(g >> 2)*SEQ + (g & 3)*8);
        }
#pragma unroll
        for (int i = 0; i < 4; ++i) {
            int g = i*256 + tid;
            int key = g >> 5, c8 = (g & 31)*8;
            *(bf16x8*)(&Kbuf[0][key*256 + (c8 ^ ((key & 7) << 3))]) = kr[i];
            int dd = g >> 2, c = g & 3;
            *(bf16x8*)(&Vbuf[0][dd*VSTR + c*8]) = vr[i];
        }
    }
    __syncthreads();
    const int Lb = imax(imax(sLb[0], sLb[1]), imax(sLb[2], sLb[3]));
    const int ktEnd = imin(KPER/32, (imax(0, Lb - kb0) + 31) >> 5);

    int cur = 0;
    for (int kt = 0; kt < ktEnd; ++kt) {
        const int kb = kb0 + kt*32;
        const bool more = (kt + 1 < ktEnd);   // block-uniform
        if (more) {   // T14: issue next tile's loads; they drain under compute
            const bf16* Ks = Ksrc0 + (size_t)(kb + 32)*DIM;
            const bf16* Vs = Vsrc0 + (kb + 32);
#pragma unroll
            for (int i = 0; i < 4; ++i) {
                int g = i*256 + tid;
                kr[i] = *(const bf16x8*)(Ks + (size_t)(g >> 5)*DIM + (g & 31)*8);
                vr[i] = *(const bf16x8*)(Vs + (size_t)(g >> 2)*SEQ + (g & 3)*8);
            }
        }
        const bf16* Kc = Kbuf[cur];
        const bf16* Vc = Vbuf[cur];

        if (kb < Lw) {   // wave-uniform
            // ---- QK^T swapped: S^T[key][q] = mfma(K, Q) ----
            f32x4 s[2][2];
#pragma unroll
            for (int mt = 0; mt < 2; ++mt)
#pragma unroll
                for (int n = 0; n < 2; ++n) s[mt][n] = (f32x4){0.f,0.f,0.f,0.f};
            __builtin_amdgcn_s_setprio(1);
#pragma unroll
            for (int kk = 0; kk < 8; ++kk) {
                const int koff = kk*32 + 8*lhi;
                bf16x8 kf[2];
#pragma unroll
                for (int n = 0; n < 2; ++n) {
                    int key = n*16 + l16;
                    kf[n] = *(const bf16x8*)(Kc + key*256 + (koff ^ ((key & 7) << 3)));
                }
#pragma unroll
                for (int mt = 0; mt < 2; ++mt)
#pragma unroll
                    for (int n = 0; n < 2; ++n)
                        s[mt][n] = __builtin_amdgcn_mfma_f32_16x16x32_bf16(kf[n], qf[mt][kk], s[mt][n], 0, 0, 0);
            }
            __builtin_amdgcn_s_setprio(0);

            // ---- mask + online softmax; lane owns q-row = l16 per mt ----
            float pv[2][2][4], tmax[2];
#pragma unroll
            for (int mt = 0; mt < 2; ++mt) {
                const int L = mt ? Lq1 : Lq0;
                float tm = NEGV;
#pragma unroll
                for (int n = 0; n < 2; ++n)
#pragma unroll
                    for (int r = 0; r < 4; ++r) {
                        const int key = kb + n*16 + 4*lhi + r;
                        float v = (key < L) ? s[mt][n][r] : NEGV;
                        pv[mt][n][r] = v;
                        tm = fmaxf(tm, v);
                    }
                tm = fmaxf(tm, __shfl_xor(tm, 16));
                tm = fmaxf(tm, __shfl_xor(tm, 32));
                tmax[mt] = tm;
            }
            // T13 defer-rescale
            bool need = (tmax[0] > m_run[0] + 8.f) || (tmax[1] > m_run[1] + 8.f);
            if (__any(need)) {
#pragma unroll
                for (int mt = 0; mt < 2; ++mt) {
                    float M = fmaxf(m_run[mt], tmax[mt]);
                    float sc = __expf(m_run[mt] - M);
                    m_run[mt] = M;
                    l_run[mt] *= sc;
                    float scq[4];
#pragma unroll
                    for (int r = 0; r < 4; ++r) scq[r] = __shfl(sc, 4*lhi + r);
#pragma unroll
                    for (int t = 0; t < 16; ++t)
#pragma unroll
                        for (int r = 0; r < 4; ++r) oacc[mt][t][r] *= scq[r];
                }
            }
            // ---- exp + row-sum + in-register P -> A-fragment redistribution ----
            bf16x8 pa[2];
            const int srcA = l16 + ((lhi & 1) << 5);
            const int srcB = srcA + 16;
            const bool nsel = (lhi >> 1) != 0;
#pragma unroll
            for (int mt = 0; mt < 2; ++mt) {
                float rs = 0.f;
#pragma unroll
                for (int n = 0; n < 2; ++n)
#pragma unroll
                    for (int r = 0; r < 4; ++r) {
                        float e = __expf(pv[mt][n][r] - m_run[mt]);
                        pv[mt][n][r] = e;
                        rs += e;
                    }
                rs += __shfl_xor(rs, 16);
                rs += __shfl_xor(rs, 32);
                l_run[mt] += rs;

                uint p00 = pkbf(pv[mt][0][0], pv[mt][0][1]);
                uint p01 = pkbf(pv[mt][0][2], pv[mt][0][3]);
                uint p10 = pkbf(pv[mt][1][0], pv[mt][1][1]);
                uint p11 = pkbf(pv[mt][1][2], pv[mt][1][3]);
                uint a0 = (uint)__shfl((int)p00, srcA), a1 = (uint)__shfl((int)p01, srcA);
                uint a2 = (uint)__shfl((int)p10, srcA), a3 = (uint)__shfl((int)p11, srcA);
                uint b0 = (uint)__shfl((int)p00, srcB), b1 = (uint)__shfl((int)p01, srcB);
                uint b2 = (uint)__shfl((int)p10, srcB), b3 = (uint)__shfl((int)p11, srcB);
                union { bf16x8 v; uint u[4]; } W;
                W.u[0] = nsel ? a2 : a0;
                W.u[1] = nsel ? a3 : a1;
                W.u[2] = nsel ? b2 : b0;
                W.u[3] = nsel ? b3 : b1;
                pa[mt] = W.v;
            }
            // ---- PV: V-fragments shared across both M-tiles ----
            __builtin_amdgcn_s_setprio(1);
#pragma unroll
            for (int t = 0; t < 16; ++t) {
                const int d = t*16 + l16;
                bf16x8 vf = *(const bf16x8*)(Vc + d*VSTR + lhi*8);
                oacc[0][t] = __builtin_amdgcn_mfma_f32_16x16x32_bf16(pa[0], vf, oacc[0][t], 0, 0, 0);
                oacc[1][t] = __builtin_amdgcn_mfma_f32_16x16x32_bf16(pa[1], vf, oacc[1][t], 0, 0, 0);
            }
            __builtin_amdgcn_s_setprio(0);
        }

        if (more) {   // write next tile into the other buffer; 1 barrier/tile
            bf16* Kn = Kbuf[cur ^ 1];
            bf16* Vn = Vbuf[cur ^ 1];
#pragma unroll
            for (int i = 0; i < 4; ++i) {
                int g = i*256 + tid;
                int key = g >> 5, c8 = (g & 31)*8;
                *(bf16x8*)(&Kn[key*256 + (c8 ^ ((key & 7) << 3))]) = kr[i];
                int dd = g >> 2, c = g & 3;
                *(bf16x8*)(&Vn[dd*VSTR + c*8]) = vr[i];
            }
            __syncthreads();
        }
        cur ^= 1;
    }

    // ---- write partials ----
    const size_t ksOff = (size_t)ks * NROWS;
#pragma unroll
    for (int mt = 0; mt < 2; ++mt) {
        const int rp = b*SEQ + q0 + mt*16;
        if (lhi == 0) {
            pm[ksOff + rp + l16] = m_run[mt];
            pl[ksOff + rp + l16] = l_run[mt];
        }
#pragma unroll
        for (int r = 0; r < 4; ++r) {
            float* dst = pO + (ksOff + rp + 4*lhi + r)*DIM + l16;
#pragma unroll
            for (int t = 0; t < 16; ++t) dst[t*16] = oacc[mt][t][r];
        }
    }
}

// ================= merge KSPLIT partials -> att bf16 =================
__global__ __launch_bounds__(256) void merge_kernel(
    const float* __restrict__ pO, const float* __restrict__ pm,
    const float* __restrict__ pl, bf16* __restrict__ att)
{
    const int t = blockIdx.x*256 + threadIdx.x;
    const int row = t >> 5;
    const int d0 = (t & 31)*8;
    float mm[KSPLIT], M = NEGV;
#pragma unroll
    for (int s = 0; s < KSPLIT; ++s) { mm[s] = pm[s*NROWS + row]; M = fmaxf(M, mm[s]); }
    float acc[8] = {0,0,0,0,0,0,0,0};
    float wsum = 0.f;
#pragma unroll
    for (int s = 0; s < KSPLIT; ++s) {
        float e = __expf(mm[s] - M);
        wsum += e * pl[s*NROWS + row];
        const f32x4* p = (const f32x4*)(pO + ((size_t)s*NROWS + row)*DIM + d0);
        f32x4 x0 = p[0], x1 = p[1];
#pragma unroll
        for (int j = 0; j < 4; ++j) { acc[j] += e*x0[j]; acc[4+j] += e*x1[j]; }
    }
    float inv = 1.f / wsum;
    bf16x8 o;
#pragma unroll
    for (int j = 0; j < 8; ++j) o[j] = (bf16)(acc[j]*inv);
    *(bf16x8*)(att + (size_t)row*DIM + d0) = o;
}

// ================= launcher =================
extern "C" void kernel_launch(void* const* d_in, const int* in_sizes, int n_in,
                              void* d_out, int out_size, void* d_ws, size_t ws_size,
                              hipStream_t stream)
{
    (void)in_sizes; (void)n_in; (void)out_size; (void)ws_size;
    const float* queries = (const float*)d_in[0];
    const float* keys    = (const float*)d_in[1];
    const float* values  = (const float*)d_in[2];
    const int*   mask    = (const int*)  d_in[3];
    const float* Wq = (const float*)d_in[4];  const float* bq = (const float*)d_in[5];
    const float* Wk = (const float*)d_in[6];  const float* bk = (const float*)d_in[7];
    const float* Wv = (const float*)d_in[8];  const float* bv = (const float*)d_in[9];
    const float* Wo = (const float*)d_in[10]; const float* bo = (const float*)d_in[11];

    char* ws = (char*)d_ws;
    bf16* WqB = (bf16*)(ws);                       // 4 x 128 KB
    bf16* WkB = (bf16*)(ws + (size_t)(1<<17));
    bf16* WvB = (bf16*)(ws + (size_t)2*(1<<17));
    bf16* WoB = (bf16*)(ws + (size_t)3*(1<<17));
    float* pm = (float*)(ws + (size_t)(1<<19));    // KSPLIT*16384*4 = 256 KB
    float* pl = (float*)(ws + (size_t)(1<<19) + (size_t)(1<<18));
    bf16* Qp  = (bf16*)(ws + (size_t)(1<<20));                      // 8 MB
    bf16* Kp  = (bf16*)(ws + (size_t)(1<<20) + (size_t)(1<<23));    // 8 MB
    bf16* Vt  = (bf16*)(ws + (size_t)(1<<20) + (size_t)2*(1<<23));  // 8 MB
    bf16* att = (bf16*)(ws + (size_t)(1<<20) + (size_t)3*(1<<23));  // 8 MB
    float* pO = (float*)(ws + (size_t)(1<<20) + (size_t)4*(1<<23)); // KSPLIT*16 MB = 64 MB

    cvt_w_kernel<<<dim3(64,4), 256, 0, stream>>>(Wq, Wk, Wv, Wo, WqB, WkB, WvB, WoB);
    proj_kernel<0,false,true ><<<dim3(1024), 256, 0, stream>>>(queries, WqB, bq, Qp);
    proj_kernel<0,false,false><<<dim3(1024), 256, 0, stream>>>(keys,    WkB, bk, Kp);
    proj_kernel<1,false,false><<<dim3(1024), 256, 0, stream>>>(values,  WvB, bv, Vt);
    attn_kernel<<<dim3(512), 256, 0, stream>>>(Qp, Kp, Vt, mask, pm, pl, pO);
    merge_kernel<<<dim3(NROWS*32/256), 256, 0, stream>>>(pO, pm, pl, att);
    proj_kernel<2,true,false><<<dim3(1024), 256, 0, stream>>>(att, WoB, bo, d_out);
}

// Round 8
// 285.946 us; speedup vs baseline: 1.6278x; 1.6278x over previous
//
#include <hip/hip_runtime.h>
#include <hip/hip_bf16.h>

typedef __bf16 bf16;
typedef __attribute__((ext_vector_type(8))) bf16 bf16x8;
typedef __attribute__((ext_vector_type(4))) bf16 bf16x4;
typedef __attribute__((ext_vector_type(4))) float f32x4;
typedef unsigned int uint;

#define SEQ    4096
#define DIM    256
#define NBATCH 4
#define NROWS  (NBATCH*SEQ)      // 16384
#define NEGV   (-6.25e7f)        // -1e9 / sqrt(256)
#define KSPLIT 4
#define KPER   (SEQ/KSPLIT)      // 1024
#define VSTR   40                // V row stride: 32 keys (64B) + 16B pad

__device__ __forceinline__ int imax(int a, int b) { return a > b ? a : b; }
__device__ __forceinline__ int imin(int a, int b) { return a < b ? a : b; }

__device__ __forceinline__ uint pkbf(float lo, float hi) {
    union { bf16 b; unsigned short s; } a, c;
    a.b = (bf16)lo; c.b = (bf16)hi;
    return ((uint)c.s << 16) | (uint)a.s;
}

// ================= weights f32 -> bf16 =================
__global__ __launch_bounds__(256) void cvt_w_kernel(
    const float* __restrict__ w0, const float* __restrict__ w1,
    const float* __restrict__ w2, const float* __restrict__ w3,
    bf16* __restrict__ o0, bf16* __restrict__ o1,
    bf16* __restrict__ o2, bf16* __restrict__ o3)
{
    const float* s; bf16* d;
    switch (blockIdx.y) {
        case 0:  s = w0; d = o0; break;
        case 1:  s = w1; d = o1; break;
        case 2:  s = w2; d = o2; break;
        default: s = w3; d = o3; break;
    }
    int i = (blockIdx.x*256 + threadIdx.x)*4;
    f32x4 v = *(const f32x4*)(s + i);
    bf16x4 b;
#pragma unroll
    for (int j = 0; j < 4; ++j) b[j] = (bf16)v[j];
    *(bf16x4*)(d + i) = b;
}

// ================= fused Q/K/V projection =================
// grid (256, 3): y=0 Q (scaled 1/16, bf16 rm), y=1 K (bf16 rm), y=2 V (bf16 transposed).
// Token tile 64, 4 waves x 64 out-cols, acc 4x4.
__global__ __launch_bounds__(256, 2) void qkv_kernel(
    const float* __restrict__ q_in, const float* __restrict__ k_in,
    const float* __restrict__ v_in,
    const bf16* __restrict__ WqB, const bf16* __restrict__ WkB,
    const bf16* __restrict__ WvB,
    const float* __restrict__ bq, const float* __restrict__ bk,
    const float* __restrict__ bv,
    bf16* __restrict__ Qp, bf16* __restrict__ Kp, bf16* __restrict__ Vt)
{
    const int which = blockIdx.y;
    const float* X    = which == 0 ? q_in : which == 1 ? k_in : v_in;
    const bf16*  W    = which == 0 ? WqB  : which == 1 ? WkB  : WvB;
    const float* bias = which == 0 ? bq   : which == 1 ? bk   : bv;

    __shared__ bf16 X_lds[64*256];   // 32 KB, XOR-swizzled
    const int tid = threadIdx.x;
    const int tok0 = blockIdx.x * 64;

#pragma unroll
    for (int i = 0; i < 8; ++i) {
        int g = i*256 + tid;
        int tok = g >> 5, c8 = (g & 31)*8;
        const f32x4* p = (const f32x4*)(X + (size_t)(tok0+tok)*DIM + c8);
        f32x4 a = p[0], b2 = p[1];
        bf16x8 v;
#pragma unroll
        for (int j = 0; j < 4; ++j) { v[j] = (bf16)a[j]; v[4+j] = (bf16)b2[j]; }
        *(bf16x8*)(X_lds + tok*256 + (c8 ^ ((tok & 7) << 3))) = v;
    }
    __syncthreads();

    const int wave = tid >> 6, lane = tid & 63;
    const int l16 = lane & 15, lhi = lane >> 4;
    const int oc0 = wave * 64;

    f32x4 acc[4][4];
#pragma unroll
    for (int m = 0; m < 4; ++m)
#pragma unroll
        for (int n = 0; n < 4; ++n) acc[m][n] = (f32x4){0.f,0.f,0.f,0.f};

#pragma unroll
    for (int kk = 0; kk < 8; ++kk) {
        const int koff = kk*32 + 8*lhi;
        bf16x8 af[4], bf_[4];
#pragma unroll
        for (int m = 0; m < 4; ++m) {
            int row = m*16 + l16;
            af[m] = *(const bf16x8*)(X_lds + row*256 + (koff ^ ((row & 7) << 3)));
        }
#pragma unroll
        for (int n = 0; n < 4; ++n) {
            int o = oc0 + n*16 + l16;
            bf_[n] = *(const bf16x8*)(W + (size_t)o*DIM + koff);
        }
#pragma unroll
        for (int m = 0; m < 4; ++m)
#pragma unroll
            for (int n = 0; n < 4; ++n)
                acc[m][n] = __builtin_amdgcn_mfma_f32_16x16x32_bf16(af[m], bf_[n], acc[m][n], 0, 0, 0);
    }

#pragma unroll
    for (int n = 0; n < 4; ++n) {
        const int o = oc0 + n*16 + l16;
        const float bb = bias[o];
#pragma unroll
        for (int m = 0; m < 4; ++m) {
            const int tk0 = tok0 + m*16 + lhi*4;
            if (which == 2) {
                bf16x4 pk;
#pragma unroll
                for (int r = 0; r < 4; ++r) pk[r] = (bf16)(acc[m][n][r] + bb);
                const int bi = tk0 >> 12, tk = tk0 & (SEQ-1);
                *(bf16x4*)(Vt + (size_t)bi*DIM*SEQ + (size_t)o*SEQ + tk) = pk;
            } else {
                bf16* dst = (which == 0) ? Qp : Kp;
                const float sc = (which == 0) ? 0.0625f : 1.0f;
#pragma unroll
                for (int r = 0; r < 4; ++r)
                    dst[(size_t)(tk0+r)*DIM + o] = (bf16)((acc[m][n][r] + bb)*sc);
            }
        }
    }
}

// ================= flash attention v5 =================
// 8 waves x 32 q-rows = 256 rows/block. KVBLK=32 double-buffered (1 barrier/tile).
// KSPLIT=4, grid 256 (1/CU, 2 waves/SIMD). Panel(b,ks) pinned to XCD:
// XCD x = blockIdx&7 owns panels {2x,2x+1}; 16 lockstep blocks share each 1MB panel.
__global__ __launch_bounds__(512, 2) void attn_kernel(
    const bf16* __restrict__ Qp, const bf16* __restrict__ Kp,
    const bf16* __restrict__ Vt, const int* __restrict__ mask,
    float* __restrict__ pm, float* __restrict__ pl, float* __restrict__ pO)
{
    __shared__ __align__(16) bf16 Kbuf[2][32*256];    // 2 x 16 KB, XOR-swizzled rows
    __shared__ __align__(16) bf16 Vbuf[2][256*VSTR];  // 2 x 20 KB, 80B row stride
    __shared__ int sLb[8];

    const int tid  = threadIdx.x;
    const int wave = tid >> 6, lane = tid & 63;
    const int l16  = lane & 15, lhi = lane >> 4;

    // panel <-> XCD pinning (assumes round-robin blockIdx%8 -> XCD)
    const int xcd   = blockIdx.x & 7;
    const int jj    = blockIdx.x >> 3;        // 0..31 within XCD
    const int panel = (xcd << 1) | (jj >> 4); // 0..15
    const int qt    = jj & 15;
    const int b     = panel >> 2;
    const int ks    = panel & 3;

    const int kb0 = ks * KPER;
    const int q0  = qt*256 + wave*32;
    const size_t bQ = (size_t)b * SEQ * DIM;

    // lengths: lane (lane&31) holds row q0+(lane&31)
    const int mv = mask[b*SEQ + q0 + (lane & 31)];
    int Lw = mv;
#pragma unroll
    for (int w = 1; w < 32; w <<= 1) Lw = imax(Lw, __shfl_xor(Lw, w));
    const int Lq0 = __shfl(mv, l16);
    const int Lq1 = __shfl(mv, 16 + l16);
    if (lane == 0) sLb[wave] = Lw;

    // Q fragments (B-operand of swapped QK)
    bf16x8 qf[2][8];
#pragma unroll
    for (int mt = 0; mt < 2; ++mt) {
        const bf16* qr = Qp + bQ + (size_t)(q0 + mt*16 + l16)*DIM + 8*lhi;
#pragma unroll
        for (int kk = 0; kk < 8; ++kk) qf[mt][kk] = *(const bf16x8*)(qr + kk*32);
    }

    float m_run[2] = {NEGV, NEGV}, l_run[2] = {0.f, 0.f};
    f32x4 oacc[2][16];
#pragma unroll
    for (int mt = 0; mt < 2; ++mt)
#pragma unroll
        for (int t = 0; t < 16; ++t) oacc[mt][t] = (f32x4){0.f,0.f,0.f,0.f};

    const bf16* Ksrc0 = Kp + bQ;
    const bf16* Vsrc0 = Vt + (size_t)b * DIM * SEQ;

    bf16x8 kr[2], vr[2];
    // prologue: stage tile 0
    {
        const bf16* Ks = Ksrc0 + (size_t)kb0*DIM;
        const bf16* Vs = Vsrc0 + kb0;
#pragma unroll
        for (int i = 0; i < 2; ++i) {
            int g = i*512 + tid;
            kr[i] = *(const bf16x8*)(Ks + (size_t)(g >> 5)*DIM + (g & 31)*8);
            vr[i] = *(const bf16x8*)(Vs + (size_t)(g >> 2)*SEQ + (g & 3)*8);
        }
#pragma unroll
        for (int i = 0; i < 2; ++i) {
            int g = i*512 + tid;
            int key = g >> 5, c8 = (g & 31)*8;
            *(bf16x8*)(&Kbuf[0][key*256 + (c8 ^ ((key & 7) << 3))]) = kr[i];
            int dd = g >> 2, c = g & 3;
            *(bf16x8*)(&Vbuf[0][dd*VSTR + c*8]) = vr[i];
        }
    }
    __syncthreads();
    int Lb = sLb[0];
#pragma unroll
    for (int w = 1; w < 8; ++w) Lb = imax(Lb, sLb[w]);
    const int ktEnd = imin(KPER/32, (imax(0, Lb - kb0) + 31) >> 5);

    int cur = 0;
    for (int kt = 0; kt < ktEnd; ++kt) {
        const int kb = kb0 + kt*32;
        const bool more = (kt + 1 < ktEnd);   // block-uniform
        if (more) {   // T14: issue next tile's loads; they drain under compute
            const bf16* Ks = Ksrc0 + (size_t)(kb + 32)*DIM;
            const bf16* Vs = Vsrc0 + (kb + 32);
#pragma unroll
            for (int i = 0; i < 2; ++i) {
                int g = i*512 + tid;
                kr[i] = *(const bf16x8*)(Ks + (size_t)(g >> 5)*DIM + (g & 31)*8);
                vr[i] = *(const bf16x8*)(Vs + (size_t)(g >> 2)*SEQ + (g & 3)*8);
            }
        }
        const bf16* Kc = Kbuf[cur];
        const bf16* Vc = Vbuf[cur];

        if (kb < Lw) {   // wave-uniform
            // ---- QK^T swapped: S^T[key][q] = mfma(K, Q) ----
            f32x4 s[2][2];
#pragma unroll
            for (int mt = 0; mt < 2; ++mt)
#pragma unroll
                for (int n = 0; n < 2; ++n) s[mt][n] = (f32x4){0.f,0.f,0.f,0.f};
            __builtin_amdgcn_s_setprio(1);
#pragma unroll
            for (int kk = 0; kk < 8; ++kk) {
                const int koff = kk*32 + 8*lhi;
                bf16x8 kf[2];
#pragma unroll
                for (int n = 0; n < 2; ++n) {
                    int key = n*16 + l16;
                    kf[n] = *(const bf16x8*)(Kc + key*256 + (koff ^ ((key & 7) << 3)));
                }
#pragma unroll
                for (int mt = 0; mt < 2; ++mt)
#pragma unroll
                    for (int n = 0; n < 2; ++n)
                        s[mt][n] = __builtin_amdgcn_mfma_f32_16x16x32_bf16(kf[n], qf[mt][kk], s[mt][n], 0, 0, 0);
            }
            __builtin_amdgcn_s_setprio(0);

            // ---- mask + online softmax; lane owns q-row = l16 per mt ----
            float pv[2][2][4], tmax[2];
#pragma unroll
            for (int mt = 0; mt < 2; ++mt) {
                const int L = mt ? Lq1 : Lq0;
                float tm = NEGV;
#pragma unroll
                for (int n = 0; n < 2; ++n)
#pragma unroll
                    for (int r = 0; r < 4; ++r) {
                        const int key = kb + n*16 + 4*lhi + r;
                        float v = (key < L) ? s[mt][n][r] : NEGV;
                        pv[mt][n][r] = v;
                        tm = fmaxf(tm, v);
                    }
                tm = fmaxf(tm, __shfl_xor(tm, 16));
                tm = fmaxf(tm, __shfl_xor(tm, 32));
                tmax[mt] = tm;
            }
            // T13 defer-rescale
            bool need = (tmax[0] > m_run[0] + 8.f) || (tmax[1] > m_run[1] + 8.f);
            if (__any(need)) {
#pragma unroll
                for (int mt = 0; mt < 2; ++mt) {
                    float M = fmaxf(m_run[mt], tmax[mt]);
                    float sc = __expf(m_run[mt] - M);
                    m_run[mt] = M;
                    l_run[mt] *= sc;
                    float scq[4];
#pragma unroll
                    for (int r = 0; r < 4; ++r) scq[r] = __shfl(sc, 4*lhi + r);
#pragma unroll
                    for (int t = 0; t < 16; ++t)
#pragma unroll
                        for (int r = 0; r < 4; ++r) oacc[mt][t][r] *= scq[r];
                }
            }
            // ---- exp + row-sum + in-register P -> A-fragment redistribution ----
            bf16x8 pa[2];
            const int srcA = l16 + ((lhi & 1) << 5);
            const int srcB = srcA + 16;
            const bool nsel = (lhi >> 1) != 0;
#pragma unroll
            for (int mt = 0; mt < 2; ++mt) {
                float rs = 0.f;
#pragma unroll
                for (int n = 0; n < 2; ++n)
#pragma unroll
                    for (int r = 0; r < 4; ++r) {
                        float e = __expf(pv[mt][n][r] - m_run[mt]);
                        pv[mt][n][r] = e;
                        rs += e;
                    }
                rs += __shfl_xor(rs, 16);
                rs += __shfl_xor(rs, 32);
                l_run[mt] += rs;

                uint p00 = pkbf(pv[mt][0][0], pv[mt][0][1]);
                uint p01 = pkbf(pv[mt][0][2], pv[mt][0][3]);
                uint p10 = pkbf(pv[mt][1][0], pv[mt][1][1]);
                uint p11 = pkbf(pv[mt][1][2], pv[mt][1][3]);
                uint a0 = (uint)__shfl((int)p00, srcA), a1 = (uint)__shfl((int)p01, srcA);
                uint a2 = (uint)__shfl((int)p10, srcA), a3 = (uint)__shfl((int)p11, srcA);
                uint b0 = (uint)__shfl((int)p00, srcB), b1 = (uint)__shfl((int)p01, srcB);
                uint b2 = (uint)__shfl((int)p10, srcB), b3 = (uint)__shfl((int)p11, srcB);
                union { bf16x8 v; uint u[4]; } W;
                W.u[0] = nsel ? a2 : a0;
                W.u[1] = nsel ? a3 : a1;
                W.u[2] = nsel ? b2 : b0;
                W.u[3] = nsel ? b3 : b1;
                pa[mt] = W.v;
            }
            // ---- PV: V-fragments shared across both M-tiles ----
            __builtin_amdgcn_s_setprio(1);
#pragma unroll
            for (int t = 0; t < 16; ++t) {
                const int d = t*16 + l16;
                bf16x8 vf = *(const bf16x8*)(Vc + d*VSTR + lhi*8);
                oacc[0][t] = __builtin_amdgcn_mfma_f32_16x16x32_bf16(pa[0], vf, oacc[0][t], 0, 0, 0);
                oacc[1][t] = __builtin_amdgcn_mfma_f32_16x16x32_bf16(pa[1], vf, oacc[1][t], 0, 0, 0);
            }
            __builtin_amdgcn_s_setprio(0);
        }

        if (more) {   // write next tile into the other buffer; 1 barrier/tile
            bf16* Kn = Kbuf[cur ^ 1];
            bf16* Vn = Vbuf[cur ^ 1];
#pragma unroll
            for (int i = 0; i < 2; ++i) {
                int g = i*512 + tid;
                int key = g >> 5, c8 = (g & 31)*8;
                *(bf16x8*)(&Kn[key*256 + (c8 ^ ((key & 7) << 3))]) = kr[i];
                int dd = g >> 2, c = g & 3;
                *(bf16x8*)(&Vn[dd*VSTR + c*8]) = vr[i];
            }
            __syncthreads();
        }
        cur ^= 1;
    }

    // ---- write partials ----
    const size_t ksOff = (size_t)ks * NROWS;
#pragma unroll
    for (int mt = 0; mt < 2; ++mt) {
        const int rp = b*SEQ + q0 + mt*16;
        if (lhi == 0) {
            pm[ksOff + rp + l16] = m_run[mt];
            pl[ksOff + rp + l16] = l_run[mt];
        }
#pragma unroll
        for (int r = 0; r < 4; ++r) {
            float* dst = pO + (ksOff + rp + 4*lhi + r)*DIM + l16;
#pragma unroll
            for (int t = 0; t < 16; ++t) dst[t*16] = oacc[mt][t][r];
        }
    }
}

// ================= fused merge + output projection =================
// Token tile 64. Staging pass combines the KSPLIT partials (flash merge) into
// bf16 att rows directly in LDS, then standard GEMM vs Wo. Out: f32 d_out.
__global__ __launch_bounds__(256, 2) void oproj_kernel(
    const float* __restrict__ pO, const float* __restrict__ pm,
    const float* __restrict__ pl,
    const bf16* __restrict__ WoB, const float* __restrict__ bo,
    float* __restrict__ out)
{
    __shared__ bf16 X_lds[64*256];   // 32 KB
    const int tid = threadIdx.x;
    const int tok0 = blockIdx.x * 64;

#pragma unroll
    for (int i = 0; i < 8; ++i) {
        int g = i*256 + tid;
        int tok = g >> 5, c8 = (g & 31)*8;
        const int row = tok0 + tok;
        float mm[KSPLIT], M = NEGV;
#pragma unroll
        for (int s = 0; s < KSPLIT; ++s) { mm[s] = pm[s*NROWS + row]; M = fmaxf(M, mm[s]); }
        float w[KSPLIT], wsum = 0.f;
#pragma unroll
        for (int s = 0; s < KSPLIT; ++s) { w[s] = __expf(mm[s] - M); wsum += w[s]*pl[s*NROWS + row]; }
        const float inv = 1.f / wsum;
        float acc[8] = {0,0,0,0,0,0,0,0};
#pragma unroll
        for (int s = 0; s < KSPLIT; ++s) {
            const f32x4* p = (const f32x4*)(pO + ((size_t)s*NROWS + row)*DIM + c8);
            f32x4 x0 = p[0], x1 = p[1];
#pragma unroll
            for (int j = 0; j < 4; ++j) { acc[j] += w[s]*x0[j]; acc[4+j] += w[s]*x1[j]; }
        }
        bf16x8 v;
#pragma unroll
        for (int j = 0; j < 8; ++j) v[j] = (bf16)(acc[j]*inv);
        *(bf16x8*)(X_lds + tok*256 + (c8 ^ ((tok & 7) << 3))) = v;
    }
    __syncthreads();

    const int wave = tid >> 6, lane = tid & 63;
    const int l16 = lane & 15, lhi = lane >> 4;
    const int oc0 = wave * 64;

    f32x4 acc[4][4];
#pragma unroll
    for (int m = 0; m < 4; ++m)
#pragma unroll
        for (int n = 0; n < 4; ++n) acc[m][n] = (f32x4){0.f,0.f,0.f,0.f};

#pragma unroll
    for (int kk = 0; kk < 8; ++kk) {
        const int koff = kk*32 + 8*lhi;
        bf16x8 af[4], bf_[4];
#pragma unroll
        for (int m = 0; m < 4; ++m) {
            int row = m*16 + l16;
            af[m] = *(const bf16x8*)(X_lds + row*256 + (koff ^ ((row & 7) << 3)));
        }
#pragma unroll
        for (int n = 0; n < 4; ++n) {
            int o = oc0 + n*16 + l16;
            bf_[n] = *(const bf16x8*)(WoB + (size_t)o*DIM + koff);
        }
#pragma unroll
        for (int m = 0; m < 4; ++m)
#pragma unroll
            for (int n = 0; n < 4; ++n)
                acc[m][n] = __builtin_amdgcn_mfma_f32_16x16x32_bf16(af[m], bf_[n], acc[m][n], 0, 0, 0);
    }

#pragma unroll
    for (int n = 0; n < 4; ++n) {
        const int o = oc0 + n*16 + l16;
        const float bb = bo[o];
#pragma unroll
        for (int m = 0; m < 4; ++m) {
            const int tk0 = tok0 + m*16 + lhi*4;
#pragma unroll
            for (int r = 0; r < 4; ++r)
                out[(size_t)(tk0+r)*DIM + o] = acc[m][n][r] + bb;
        }
    }
}

// ================= launcher =================
extern "C" void kernel_launch(void* const* d_in, const int* in_sizes, int n_in,
                              void* d_out, int out_size, void* d_ws, size_t ws_size,
                              hipStream_t stream)
{
    (void)in_sizes; (void)n_in; (void)out_size; (void)ws_size;
    const float* queries = (const float*)d_in[0];
    const float* keys    = (const float*)d_in[1];
    const float* values  = (const float*)d_in[2];
    const int*   mask    = (const int*)  d_in[3];
    const float* Wq = (const float*)d_in[4];  const float* bq = (const float*)d_in[5];
    const float* Wk = (const float*)d_in[6];  const float* bk = (const float*)d_in[7];
    const float* Wv = (const float*)d_in[8];  const float* bv = (const float*)d_in[9];
    const float* Wo = (const float*)d_in[10]; const float* bo = (const float*)d_in[11];

    char* ws = (char*)d_ws;
    bf16* WqB = (bf16*)(ws);                       // 4 x 128 KB
    bf16* WkB = (bf16*)(ws + (size_t)(1<<17));
    bf16* WvB = (bf16*)(ws + (size_t)2*(1<<17));
    bf16* WoB = (bf16*)(ws + (size_t)3*(1<<17));
    float* pm = (float*)(ws + (size_t)(1<<19));    // KSPLIT*16384*4 = 256 KB
    float* pl = (float*)(ws + (size_t)(1<<19) + (size_t)(1<<18));
    bf16* Qp  = (bf16*)(ws + (size_t)(1<<20));                      // 8 MB
    bf16* Kp  = (bf16*)(ws + (size_t)(1<<20) + (size_t)(1<<23));    // 8 MB
    bf16* Vt  = (bf16*)(ws + (size_t)(1<<20) + (size_t)2*(1<<23));  // 8 MB
    float* pO = (float*)(ws + (size_t)(1<<20) + (size_t)4*(1<<23)); // 64 MB

    cvt_w_kernel<<<dim3(64,4), 256, 0, stream>>>(Wq, Wk, Wv, Wo, WqB, WkB, WvB, WoB);
    qkv_kernel<<<dim3(256,3), 256, 0, stream>>>(queries, keys, values,
                                                WqB, WkB, WvB, bq, bk, bv, Qp, Kp, Vt);
    attn_kernel<<<dim3(256), 512, 0, stream>>>(Qp, Kp, Vt, mask, pm, pl, pO);
    oproj_kernel<<<dim3(256), 256, 0, stream>>>(pO, pm, pl, WoB, bo, (float*)d_out);
}